// Round 1
// baseline (7628.835 us; speedup 1.0000x reference)
//
#include <hip/hip_runtime.h>
#include <hip/hip_bf16.h>

#define NB 256
#define TT 128
#define DD 1024
#define HH 1024
#define FH 4096
#define KTOT 3072

typedef __attribute__((ext_vector_type(8))) short short8;
typedef __attribute__((ext_vector_type(4))) float f32x4;

__device__ __forceinline__ unsigned short f2bf(float f) {
    union { float f; unsigned u; } v;
    v.f = f;
    unsigned u = v.u;
    u += 0x7FFFu + ((u >> 16) & 1u);   // round-to-nearest-even
    return (unsigned short)(u >> 16);
}

__device__ __forceinline__ float sigm(float v) { return 1.f / (1.f + __expf(-v)); }
__device__ __forceinline__ float tanhfast(float v) { return 1.f - 2.f / (__expf(2.f * v) + 1.f); }

// ---------------------------------------------------------------------------
// Prep: Wt[c][k] bf16, c in [0,4096), k = concat(Wx:0..1023, Wh:1024..2047, Wattn:2048..3071)
// Wt[c][k] = Wseg[k_local][c]  (transposed so GEMM B-fragments are contiguous in k)
// ---------------------------------------------------------------------------
__global__ __launch_bounds__(256) void wt_prep(const float* __restrict__ Wx,
                                               const float* __restrict__ Wh,
                                               const float* __restrict__ Wattn,
                                               unsigned short* __restrict__ Wt) {
    __shared__ unsigned short tile[64][65];
    int k0 = blockIdx.x * 64;   // 48 blocks
    int c0 = blockIdx.y * 64;   // 64 blocks
    const float* src; int kl0;
    if (k0 < 1024)      { src = Wx;    kl0 = k0; }
    else if (k0 < 2048) { src = Wh;    kl0 = k0 - 1024; }
    else                { src = Wattn; kl0 = k0 - 2048; }
    int tid = threadIdx.x;
    int r = tid >> 2;             // 0..63
    int ch = (tid & 3) << 4;      // 0,16,32,48
    const float* p = src + (size_t)(kl0 + r) * FH + c0 + ch;
#pragma unroll
    for (int i = 0; i < 16; i += 4) {
        float4 v = *reinterpret_cast<const float4*>(p + i);
        tile[r][ch + i + 0] = f2bf(v.x);
        tile[r][ch + i + 1] = f2bf(v.y);
        tile[r][ch + i + 2] = f2bf(v.z);
        tile[r][ch + i + 3] = f2bf(v.w);
    }
    __syncthreads();
    alignas(16) unsigned short vals[16];
#pragma unroll
    for (int i = 0; i < 16; ++i) vals[i] = tile[ch + i][r];
    unsigned short* q = Wt + (size_t)(c0 + r) * KTOT + k0 + ch;
    *reinterpret_cast<uint4*>(q)     = *reinterpret_cast<uint4*>(&vals[0]);
    *reinterpret_cast<uint4*>(q + 8) = *reinterpret_cast<uint4*>(&vals[8]);
}

// ---------------------------------------------------------------------------
// h0 = c0 = mean over 16 spatial locations of Af
// ---------------------------------------------------------------------------
__global__ __launch_bounds__(256) void init_h0(const float* __restrict__ A,
                                               float* __restrict__ h,
                                               float* __restrict__ c) {
    int idx = blockIdx.x * 256 + threadIdx.x;      // 0 .. N*H
    const float4* p = reinterpret_cast<const float4*>(A + (size_t)idx * 16);
    float s = 0.f;
#pragma unroll
    for (int q = 0; q < 4; ++q) {
        float4 v = p[q];
        s += v.x + v.y + v.z + v.w;
    }
    float m = s * 0.0625f;
    h[idx] = m;
    c[idx] = m;
}

// ---------------------------------------------------------------------------
// attention: one block per n, 256 threads, thread t owns h-rows 4t..4t+3
// logits[l] = (1/32) * sum_h h[n,h]*Af[n,h,l]; softmax; attn[n,h]=sum_l Af*w
// ---------------------------------------------------------------------------
__device__ __forceinline__ void attn_compute(int n, int tid, const float hv[4],
                                             const float* __restrict__ A,
                                             float* __restrict__ attn) {
    __shared__ float red[4][16];
    __shared__ float wsm[16];
    float lg[16];
#pragma unroll
    for (int l = 0; l < 16; ++l) lg[l] = 0.f;
    const float* base = A + ((size_t)n * HH + 4 * (size_t)tid) * 16;
#pragma unroll
    for (int e = 0; e < 4; ++e) {
        float hval = hv[e];
        const float4* pe = reinterpret_cast<const float4*>(base + e * 16);
#pragma unroll
        for (int q = 0; q < 4; ++q) {
            float4 af = pe[q];
            lg[q * 4 + 0] += hval * af.x;
            lg[q * 4 + 1] += hval * af.y;
            lg[q * 4 + 2] += hval * af.z;
            lg[q * 4 + 3] += hval * af.w;
        }
    }
#pragma unroll
    for (int l = 0; l < 16; ++l) {
#pragma unroll
        for (int off = 1; off < 64; off <<= 1)
            lg[l] += __shfl_xor(lg[l], off);
    }
    int wave = tid >> 6, lane = tid & 63;
    if (lane == 0) {
#pragma unroll
        for (int l = 0; l < 16; ++l) red[wave][l] = lg[l];
    }
    __syncthreads();
    if (tid < 16) {
        float s = (red[0][tid] + red[1][tid] + red[2][tid] + red[3][tid]) * 0.03125f;
        float m = s;
        m = fmaxf(m, __shfl_xor(m, 1));
        m = fmaxf(m, __shfl_xor(m, 2));
        m = fmaxf(m, __shfl_xor(m, 4));
        m = fmaxf(m, __shfl_xor(m, 8));
        float e = __expf(s - m);
        float d = e;
        d += __shfl_xor(d, 1);
        d += __shfl_xor(d, 2);
        d += __shfl_xor(d, 4);
        d += __shfl_xor(d, 8);
        wsm[tid] = e / d;
    }
    __syncthreads();
    float w[16];
#pragma unroll
    for (int l = 0; l < 16; ++l) w[l] = wsm[l];
#pragma unroll
    for (int e = 0; e < 4; ++e) {
        const float* pe = base + e * 16;
        float a = 0.f;
#pragma unroll
        for (int l = 0; l < 16; ++l) a += pe[l] * w[l];
        attn[(size_t)n * HH + 4 * tid + e] = a;
    }
}

__global__ __launch_bounds__(256) void attn_init_kernel(const float* __restrict__ h,
                                                        const float* __restrict__ A,
                                                        float* __restrict__ attn) {
    int n = blockIdx.x, tid = threadIdx.x;
    float4 h4 = *reinterpret_cast<const float4*>(h + (size_t)n * HH + tid * 4);
    float hv[4] = {h4.x, h4.y, h4.z, h4.w};
    attn_compute(n, tid, hv, A, attn);
}

// ---------------------------------------------------------------------------
// Gate GEMM: pre[n][col] = sum_k Acat[n][k] * Wt[col][k]
//   Acat = [x_t (fp32->bf16) | h | attn], K = 3072, M = 256, Ncols = 4096
// 64x64 tile, BK=64, 4 waves (2x2), each wave 32x32 via 2x2 mfma 16x16x32 frags
// ---------------------------------------------------------------------------
__global__ __launch_bounds__(256) void gemm_gates(const float* __restrict__ x,
                                                  const float* __restrict__ h,
                                                  const float* __restrict__ attn,
                                                  const unsigned short* __restrict__ Wt,
                                                  float* __restrict__ pre, int tstep) {
    __shared__ unsigned short Asm[64][72];
    __shared__ unsigned short Bsm[64][72];
    int bn = blockIdx.x;   // 0..63
    int bm = blockIdx.y;   // 0..3
    int tid = threadIdx.x;
    int wave = tid >> 6, lane = tid & 63;
    int wm = wave >> 1, wn = wave & 1;

    f32x4 acc[2][2];
#pragma unroll
    for (int mi = 0; mi < 2; ++mi)
#pragma unroll
        for (int ni = 0; ni < 2; ++ni)
#pragma unroll
            for (int e = 0; e < 4; ++e) acc[mi][ni][e] = 0.f;

    int r = tid >> 2;            // 0..63 row within tile
    int ch = (tid & 3) << 4;     // element chunk 0/16/32/48
    int nrow = bm * 64 + r;
    int crow = bn * 64 + r;

    for (int kt = 0; kt < 48; ++kt) {
        int kk = (kt << 6) + ch;
        const float* ap;
        if (kk < 1024)      ap = x + ((size_t)nrow * TT + tstep) * DD + kk;
        else if (kk < 2048) ap = h + (size_t)nrow * HH + (kk - 1024);
        else                ap = attn + (size_t)nrow * HH + (kk - 2048);
        alignas(16) unsigned short av[16];
#pragma unroll
        for (int i = 0; i < 16; i += 4) {
            float4 v = *reinterpret_cast<const float4*>(ap + i);
            av[i + 0] = f2bf(v.x);
            av[i + 1] = f2bf(v.y);
            av[i + 2] = f2bf(v.z);
            av[i + 3] = f2bf(v.w);
        }
        const unsigned short* bp = Wt + (size_t)crow * KTOT + kk;
        uint4 bv0 = *reinterpret_cast<const uint4*>(bp);
        uint4 bv1 = *reinterpret_cast<const uint4*>(bp + 8);

        __syncthreads();   // previous iteration's LDS reads complete
        *reinterpret_cast<uint4*>(&Asm[r][ch])     = *reinterpret_cast<uint4*>(&av[0]);
        *reinterpret_cast<uint4*>(&Asm[r][ch + 8]) = *reinterpret_cast<uint4*>(&av[8]);
        *reinterpret_cast<uint4*>(&Bsm[r][ch])     = bv0;
        *reinterpret_cast<uint4*>(&Bsm[r][ch + 8]) = bv1;
        __syncthreads();

#pragma unroll
        for (int kh = 0; kh < 2; ++kh) {
            int kb = kh * 32 + (lane >> 4) * 8;
            short8 afr[2], bfr[2];
            afr[0] = *reinterpret_cast<const short8*>(&Asm[wm * 32 + (lane & 15)][kb]);
            afr[1] = *reinterpret_cast<const short8*>(&Asm[wm * 32 + 16 + (lane & 15)][kb]);
            bfr[0] = *reinterpret_cast<const short8*>(&Bsm[wn * 32 + (lane & 15)][kb]);
            bfr[1] = *reinterpret_cast<const short8*>(&Bsm[wn * 32 + 16 + (lane & 15)][kb]);
#pragma unroll
            for (int mi = 0; mi < 2; ++mi)
#pragma unroll
                for (int ni = 0; ni < 2; ++ni)
                    acc[mi][ni] = __builtin_amdgcn_mfma_f32_16x16x32_bf16(
                        afr[mi], bfr[ni], acc[mi][ni], 0, 0, 0);
        }
    }

    int lrow = (lane >> 4) * 4;
    int lcol = lane & 15;
#pragma unroll
    for (int mi = 0; mi < 2; ++mi)
#pragma unroll
        for (int ni = 0; ni < 2; ++ni)
#pragma unroll
            for (int e = 0; e < 4; ++e) {
                int m  = bm * 64 + wm * 32 + mi * 16 + lrow + e;
                int cc = bn * 64 + wn * 32 + ni * 16 + lcol;
                pre[(size_t)m * FH + cc] = acc[mi][ni][e];
            }
}

// ---------------------------------------------------------------------------
// LSTM update (+ fused attention for the NEXT step): one block per n
// ---------------------------------------------------------------------------
__global__ __launch_bounds__(256) void update_attn_kernel(const float* __restrict__ pre,
                                                          const float* __restrict__ b,
                                                          const float* __restrict__ A,
                                                          float* __restrict__ c,
                                                          float* __restrict__ h,
                                                          float* __restrict__ attn,
                                                          float* __restrict__ out, int tstep) {
    int n = blockIdx.x;
    int tid = threadIdx.x;
    size_t rb = (size_t)n * FH;
    int j = tid * 4;
    float4 iv = *reinterpret_cast<const float4*>(pre + rb + j);
    float4 fv = *reinterpret_cast<const float4*>(pre + rb + HH + j);
    float4 ov = *reinterpret_cast<const float4*>(pre + rb + 2 * HH + j);
    float4 gv = *reinterpret_cast<const float4*>(pre + rb + 3 * HH + j);
    float4 bi = *reinterpret_cast<const float4*>(b + j);
    float4 bf = *reinterpret_cast<const float4*>(b + HH + j);
    float4 bo = *reinterpret_cast<const float4*>(b + 2 * HH + j);
    float4 bg = *reinterpret_cast<const float4*>(b + 3 * HH + j);
    float4 cv = *reinterpret_cast<const float4*>(c + (size_t)n * HH + j);

    float ia[4] = {iv.x + bi.x, iv.y + bi.y, iv.z + bi.z, iv.w + bi.w};
    float fa[4] = {fv.x + bf.x, fv.y + bf.y, fv.z + bf.z, fv.w + bf.w};
    float oa[4] = {ov.x + bo.x, ov.y + bo.y, ov.z + bo.z, ov.w + bo.w};
    float ga[4] = {gv.x + bg.x, gv.y + bg.y, gv.z + bg.z, gv.w + bg.w};
    float ca[4] = {cv.x, cv.y, cv.z, cv.w};
    float hn[4], cn[4];
#pragma unroll
    for (int e = 0; e < 4; ++e) {
        float ig = sigm(ia[e]);
        float fg = sigm(fa[e]);
        float og = sigm(oa[e]);
        float gg = tanhfast(ga[e]);
        float c2 = fg * ca[e] + ig * gg;
        cn[e] = c2;
        hn[e] = og * tanhfast(c2);
    }
    float4 cw, hw;
    cw.x = cn[0]; cw.y = cn[1]; cw.z = cn[2]; cw.w = cn[3];
    hw.x = hn[0]; hw.y = hn[1]; hw.z = hn[2]; hw.w = hn[3];
    *reinterpret_cast<float4*>(c + (size_t)n * HH + j) = cw;
    *reinterpret_cast<float4*>(h + (size_t)n * HH + j) = hw;
    *reinterpret_cast<float4*>(out + ((size_t)n * TT + tstep) * HH + j) = hw;

    // attention from the just-updated h (this is prev_h for step tstep+1)
    attn_compute(n, tid, hn, A, attn);
}

// ---------------------------------------------------------------------------
extern "C" void kernel_launch(void* const* d_in, const int* in_sizes, int n_in,
                              void* d_out, int out_size, void* d_ws, size_t ws_size,
                              hipStream_t stream) {
    const float* x     = (const float*)d_in[0];
    const float* A     = (const float*)d_in[1];
    const float* Wx    = (const float*)d_in[2];
    const float* Wh    = (const float*)d_in[3];
    const float* Wattn = (const float*)d_in[4];
    const float* b     = (const float*)d_in[5];
    float* out = (float*)d_out;

    char* ws = (char*)d_ws;
    float* h    = (float*)(ws);                         // 1 MB
    float* c    = (float*)(ws + (1u << 20));            // 1 MB
    float* attn = (float*)(ws + (2u << 20));            // 1 MB
    float* pre  = (float*)(ws + (3u << 20));            // 4 MB
    unsigned short* Wt = (unsigned short*)(ws + (8u << 20));  // 24 MB

    wt_prep<<<dim3(48, 64), 256, 0, stream>>>(Wx, Wh, Wattn, Wt);
    init_h0<<<(NB * HH) / 256, 256, 0, stream>>>(A, h, c);
    attn_init_kernel<<<NB, 256, 0, stream>>>(h, A, attn);
    for (int t = 0; t < TT; ++t) {
        gemm_gates<<<dim3(64, 4), 256, 0, stream>>>(x, h, attn, Wt, pre, t);
        update_attn_kernel<<<NB, 256, 0, stream>>>(pre, b, A, c, h, attn, out, t);
    }
}

// Round 2
// 5025.911 us; speedup vs baseline: 1.5179x; 1.5179x over previous
//
#include <hip/hip_runtime.h>
#include <hip/hip_bf16.h>

#define NB 256
#define TT 128
#define DD 1024
#define HH 1024
#define FH 4096
#define KTOT 3072

typedef __attribute__((ext_vector_type(4))) float f32x4;
typedef __attribute__((ext_vector_type(8))) short short8;

__device__ __forceinline__ unsigned short f2bf(float f) {
    union { float f; unsigned u; } v; v.f = f;
    unsigned u = v.u;
    u += 0x7FFFu + ((u >> 16) & 1u);   // RNE
    return (unsigned short)(u >> 16);
}
__device__ __forceinline__ float sigm(float v) { return 1.f / (1.f + __expf(-v)); }
__device__ __forceinline__ float tanhf_(float v) { return 1.f - 2.f / (__expf(2.f * v) + 1.f); }

// block id -> (row tile m0, j tile j0); jt aligned to XCD (bid&7) for Wt/Af L2 locality
__device__ __forceinline__ void bmap(int bid, int& m0, int& j0) {
    int x = bid & 7, y = (bid >> 3) & 7, mt = bid >> 6;
    m0 = mt * 64;
    j0 = (x * 8 + y) * 16;
}

// ---------------------------------------------------------------------------
// Wt[c][k] bf16, c = pre column (gate*1024 + j), k = concat(x,h,attn) index
// ---------------------------------------------------------------------------
__global__ __launch_bounds__(256) void wt_prep(const float* __restrict__ Wx,
                                               const float* __restrict__ Wh,
                                               const float* __restrict__ Wattn,
                                               unsigned short* __restrict__ Wt) {
    __shared__ unsigned short tile[64][65];
    int k0 = blockIdx.x * 64;   // 48
    int c0 = blockIdx.y * 64;   // 64
    const float* src; int kl0;
    if (k0 < 1024)      { src = Wx;    kl0 = k0; }
    else if (k0 < 2048) { src = Wh;    kl0 = k0 - 1024; }
    else                { src = Wattn; kl0 = k0 - 2048; }
    int tid = threadIdx.x;
    int r = tid >> 2;
    int ch = (tid & 3) << 4;
    const float* p = src + (size_t)(kl0 + r) * FH + c0 + ch;
#pragma unroll
    for (int i = 0; i < 16; i += 4) {
        float4 v = *reinterpret_cast<const float4*>(p + i);
        tile[r][ch + i + 0] = f2bf(v.x);
        tile[r][ch + i + 1] = f2bf(v.y);
        tile[r][ch + i + 2] = f2bf(v.z);
        tile[r][ch + i + 3] = f2bf(v.w);
    }
    __syncthreads();
    alignas(16) unsigned short vals[16];
#pragma unroll
    for (int i = 0; i < 16; ++i) vals[i] = tile[ch + i][r];
    unsigned short* q = Wt + (size_t)(c0 + r) * KTOT + k0 + ch;
    *reinterpret_cast<uint4*>(q)     = *reinterpret_cast<uint4*>(&vals[0]);
    *reinterpret_cast<uint4*>(q + 8) = *reinterpret_cast<uint4*>(&vals[8]);
}

__global__ __launch_bounds__(256) void zero_buf(float* __restrict__ p, int n) {
    int i = blockIdx.x * 256 + threadIdx.x;
    if (i < n) p[i] = 0.f;
}

// ---------------------------------------------------------------------------
// init: h0 = c0 = mean(Af[n,h,:]); write hcat h-slot0 (bf16) + c; logits(h0) -> lg0
// ---------------------------------------------------------------------------
__global__ __launch_bounds__(512) void init_kernel(const float* __restrict__ A,
                                                   float* __restrict__ c,
                                                   unsigned short* __restrict__ hcat,
                                                   float* __restrict__ lg0) {
    int m0, j0; bmap(blockIdx.x, m0, j0);
    int tid = threadIdx.x;
    int r = tid >> 3, j2 = (tid & 7) * 2;
    int n = m0 + r;
    float lg[16];
#pragma unroll
    for (int l = 0; l < 16; ++l) lg[l] = 0.f;
#pragma unroll
    for (int e = 0; e < 2; ++e) {
        int j = j0 + j2 + e;
        const float4* p = reinterpret_cast<const float4*>(A + ((size_t)n * HH + j) * 16);
        float4 a0 = p[0], a1 = p[1], a2 = p[2], a3 = p[3];
        float av[16] = {a0.x,a0.y,a0.z,a0.w, a1.x,a1.y,a1.z,a1.w,
                        a2.x,a2.y,a2.z,a2.w, a3.x,a3.y,a3.z,a3.w};
        float s = 0.f;
#pragma unroll
        for (int l = 0; l < 16; ++l) s += av[l];
        float m = s * 0.0625f;
        c[(size_t)n * HH + j] = m;
        hcat[(size_t)n * 3072 + j] = f2bf(m);        // h slot 0
#pragma unroll
        for (int l = 0; l < 16; ++l) lg[l] += m * av[l];
    }
#pragma unroll
    for (int l = 0; l < 16; ++l) {
        lg[l] += __shfl_xor(lg[l], 1);
        lg[l] += __shfl_xor(lg[l], 2);
        lg[l] += __shfl_xor(lg[l], 4);
    }
    int l0 = (tid & 7) * 2;
    atomicAdd(&lg0[(size_t)n * 16 + l0],     lg[l0]);
    atomicAdd(&lg0[(size_t)n * 16 + l0 + 1], lg[l0 + 1]);
}

// ---------------------------------------------------------------------------
// attn phase: softmax(logits/32) -> attn slice (bf16 into hcat[..,2048+j]);
// also zeroes the (t+2)%3 logits buffer (untouched this dispatch)
// ---------------------------------------------------------------------------
__global__ __launch_bounds__(512) void attn_phase(const float* __restrict__ lgcur,
                                                  float* __restrict__ lgz,
                                                  const float* __restrict__ A,
                                                  unsigned short* __restrict__ hcat) {
    int m0, j0; bmap(blockIdx.x, m0, j0);
    int tid = threadIdx.x;
    int r = tid >> 3, j2 = (tid & 7) * 2;
    int n = m0 + r;
    const float4* lp = reinterpret_cast<const float4*>(lgcur + (size_t)n * 16);
    float4 s0 = lp[0], s1 = lp[1], s2 = lp[2], s3 = lp[3];
    float s[16] = {s0.x,s0.y,s0.z,s0.w, s1.x,s1.y,s1.z,s1.w,
                   s2.x,s2.y,s2.z,s2.w, s3.x,s3.y,s3.z,s3.w};
    float mx = -1e30f;
#pragma unroll
    for (int l = 0; l < 16; ++l) { s[l] *= 0.03125f; mx = fmaxf(mx, s[l]); }
    float wsum = 0.f;
    float w[16];
#pragma unroll
    for (int l = 0; l < 16; ++l) { w[l] = __expf(s[l] - mx); wsum += w[l]; }
    float inv = 1.f / wsum;
#pragma unroll
    for (int e = 0; e < 2; ++e) {
        int j = j0 + j2 + e;
        const float4* p = reinterpret_cast<const float4*>(A + ((size_t)n * HH + j) * 16);
        float4 a0 = p[0], a1 = p[1], a2 = p[2], a3 = p[3];
        float av[16] = {a0.x,a0.y,a0.z,a0.w, a1.x,a1.y,a1.z,a1.w,
                        a2.x,a2.y,a2.z,a2.w, a3.x,a3.y,a3.z,a3.w};
        float acc = 0.f;
#pragma unroll
        for (int l = 0; l < 16; ++l) acc += av[l] * w[l];
        hcat[(size_t)n * 3072 + 2048 + j] = f2bf(acc * inv);
    }
    if ((blockIdx.x & 63) == 0) {     // jt == 0 blocks zero the (t+2)%3 buffer
        int l0 = (tid & 7) * 2;
        lgz[(size_t)n * 16 + l0]     = 0.f;
        lgz[(size_t)n * 16 + l0 + 1] = 0.f;
    }
}

// ---------------------------------------------------------------------------
// fused GEMM + LSTM update + logit partials
// block: rows m0..m0+64, j-cols j0..j0+16, all 4 gates. K = 3072, BK = 64.
// 8 waves: gate = w&3, kh = w>>2 (K-halves summed in LDS at epilogue).
// LDS XOR swizzle: elem (row,k) at col k ^ ((row&7)<<3)  [both sides]
// ---------------------------------------------------------------------------
__global__ __launch_bounds__(512) void gemm_fused(const float* __restrict__ x,
                                                  unsigned short* hcat,
                                                  const unsigned short* __restrict__ Wt,
                                                  const float* __restrict__ A,
                                                  const float* __restrict__ b,
                                                  float* __restrict__ c,
                                                  float* __restrict__ out,
                                                  float* __restrict__ lgnext, int t) {
    __shared__ unsigned short As[64][64];
    __shared__ unsigned short Bs[64][64];
    __shared__ float gsm[4][64][17];

    int m0, j0; bmap(blockIdx.x, m0, j0);
    int tid = threadIdx.x;
    int w = tid >> 6, lane = tid & 63;
    int gate = w & 3, kh = w >> 2;
    int hsel = t & 1;

    // staging mapping: thread -> (row 0..63, 8 k-elems)
    int srow = tid >> 3;
    int kel  = (tid & 7) << 3;
    int scol = kel ^ ((srow & 7) << 3);
    int an = m0 + srow;
    int brow = ((srow >> 4) * 1024) + j0 + (srow & 15);
    const unsigned short* bptr0 = Wt + (size_t)brow * KTOT + kel;
    const unsigned short* hrow  = hcat + (size_t)an * 3072;
    const float* xrow = x + ((size_t)an * TT + t) * DD + kel;

    uint4 ra, rb;
    auto preload = [&](int kt) {
        int k0 = kt << 6;
        if (k0 < 1024) {
            float4 v0 = *reinterpret_cast<const float4*>(xrow + k0);
            float4 v1 = *reinterpret_cast<const float4*>(xrow + k0 + 4);
            ra.x = (unsigned)f2bf(v0.x) | ((unsigned)f2bf(v0.y) << 16);
            ra.y = (unsigned)f2bf(v0.z) | ((unsigned)f2bf(v0.w) << 16);
            ra.z = (unsigned)f2bf(v1.x) | ((unsigned)f2bf(v1.y) << 16);
            ra.w = (unsigned)f2bf(v1.z) | ((unsigned)f2bf(v1.w) << 16);
        } else {
            int off = (k0 < 2048) ? (hsel * 1024 + (k0 - 1024) + kel) : (k0 + kel);
            ra = *reinterpret_cast<const uint4*>(hrow + off);
        }
        rb = *reinterpret_cast<const uint4*>(bptr0 + k0);
    };

    f32x4 acc[4];
#pragma unroll
    for (int mi = 0; mi < 4; ++mi)
#pragma unroll
        for (int e = 0; e < 4; ++e) acc[mi][e] = 0.f;

    preload(0);
    for (int kt = 0; kt < 48; ++kt) {
        if (kt) __syncthreads();               // prior compute done reading LDS
        *reinterpret_cast<uint4*>(&As[srow][scol]) = ra;
        *reinterpret_cast<uint4*>(&Bs[srow][scol]) = rb;
        if (kt + 1 < 48) preload(kt + 1);      // issue-early: latency hides under compute
        __syncthreads();

        int kbase = kh * 32 + ((lane >> 4) << 3);
        int fcol  = kbase ^ ((lane & 7) << 3);
        short8 bfr = *reinterpret_cast<const short8*>(&Bs[gate * 16 + (lane & 15)][fcol]);
#pragma unroll
        for (int mi = 0; mi < 4; ++mi) {
            short8 afr = *reinterpret_cast<const short8*>(&As[mi * 16 + (lane & 15)][fcol]);
            acc[mi] = __builtin_amdgcn_mfma_f32_16x16x32_bf16(afr, bfr, acc[mi], 0, 0, 0);
        }
    }

    // combine kh halves in LDS
    int crow = (lane >> 4) << 2;
    int ccol = lane & 15;
    if (w < 4) {
#pragma unroll
        for (int mi = 0; mi < 4; ++mi)
#pragma unroll
            for (int e = 0; e < 4; ++e)
                gsm[gate][mi * 16 + crow + e][ccol] = acc[mi][e];
    }
    __syncthreads();
    if (w >= 4) {
#pragma unroll
        for (int mi = 0; mi < 4; ++mi)
#pragma unroll
            for (int e = 0; e < 4; ++e)
                gsm[gate][mi * 16 + crow + e][ccol] += acc[mi][e];
    }
    __syncthreads();

    // LSTM update + logit partials (thread: row r, 2 j's)
    int r = tid >> 3, j2 = (tid & 7) * 2;
    int n = m0 + r;
    int j = j0 + j2;
    float2 cv = *reinterpret_cast<const float2*>(c + (size_t)n * HH + j);
    float hn[2], cn[2];
#pragma unroll
    for (int e = 0; e < 2; ++e) {
        float ig = sigm(gsm[0][r][j2 + e] + b[0 * HH + j + e]);
        float fg = sigm(gsm[1][r][j2 + e] + b[1 * HH + j + e]);
        float og = sigm(gsm[2][r][j2 + e] + b[2 * HH + j + e]);
        float gg = tanhf_(gsm[3][r][j2 + e] + b[3 * HH + j + e]);
        float cc = fg * (e ? cv.y : cv.x) + ig * gg;
        cn[e] = cc;
        hn[e] = og * tanhf_(cc);
    }
    *reinterpret_cast<float2*>(c + (size_t)n * HH + j) = make_float2(cn[0], cn[1]);
    hcat[(size_t)n * 3072 + (hsel ^ 1) * 1024 + j]     = f2bf(hn[0]);
    hcat[(size_t)n * 3072 + (hsel ^ 1) * 1024 + j + 1] = f2bf(hn[1]);
    *reinterpret_cast<float2*>(out + ((size_t)n * TT + t) * HH + j) = make_float2(hn[0], hn[1]);

    float lg[16];
#pragma unroll
    for (int l = 0; l < 16; ++l) lg[l] = 0.f;
#pragma unroll
    for (int e = 0; e < 2; ++e) {
        const float4* p = reinterpret_cast<const float4*>(A + ((size_t)n * HH + j + e) * 16);
        float4 a0 = p[0], a1 = p[1], a2 = p[2], a3 = p[3];
        float av[16] = {a0.x,a0.y,a0.z,a0.w, a1.x,a1.y,a1.z,a1.w,
                        a2.x,a2.y,a2.z,a2.w, a3.x,a3.y,a3.z,a3.w};
        float hv = hn[e];
#pragma unroll
        for (int l = 0; l < 16; ++l) lg[l] += hv * av[l];
    }
#pragma unroll
    for (int l = 0; l < 16; ++l) {
        lg[l] += __shfl_xor(lg[l], 1);
        lg[l] += __shfl_xor(lg[l], 2);
        lg[l] += __shfl_xor(lg[l], 4);
    }
    int l0 = (tid & 7) * 2;
    atomicAdd(&lgnext[(size_t)n * 16 + l0],     lg[l0]);
    atomicAdd(&lgnext[(size_t)n * 16 + l0 + 1], lg[l0 + 1]);
}

// ---------------------------------------------------------------------------
extern "C" void kernel_launch(void* const* d_in, const int* in_sizes, int n_in,
                              void* d_out, int out_size, void* d_ws, size_t ws_size,
                              hipStream_t stream) {
    const float* x     = (const float*)d_in[0];
    const float* A     = (const float*)d_in[1];
    const float* Wx    = (const float*)d_in[2];
    const float* Wh    = (const float*)d_in[3];
    const float* Wattn = (const float*)d_in[4];
    const float* b     = (const float*)d_in[5];
    float* out = (float*)d_out;

    char* ws = (char*)d_ws;
    unsigned short* Wt   = (unsigned short*)(ws);              // 25,165,824 B
    unsigned short* hcat = (unsigned short*)(ws + 25165824);   //  1,572,864 B  [h0|h1|attn]
    float* c             = (float*)(ws + 26738688);            //  1,048,576 B
    float* lg            = (float*)(ws + 27787264);            //     49,152 B  (3 bufs)

    wt_prep<<<dim3(48, 64), 256, 0, stream>>>(Wx, Wh, Wattn, Wt);
    zero_buf<<<48, 256, 0, stream>>>(lg, 3 * NB * 16);
    init_kernel<<<256, 512, 0, stream>>>(A, c, hcat, lg);
    for (int t = 0; t < TT; ++t) {
        attn_phase<<<256, 512, 0, stream>>>(lg + (t % 3) * NB * 16,
                                            lg + ((t + 2) % 3) * NB * 16, A, hcat);
        gemm_fused<<<256, 512, 0, stream>>>(x, hcat, Wt, A, b, c, out,
                                            lg + ((t + 1) % 3) * NB * 16, t);
    }
}